// Round 16
// baseline (327.393 us; speedup 1.0000x reference)
//
#include <hip/hip_runtime.h>

constexpr int kN = 50000;
constexpr int kE = 800000;
constexpr int kD = 128;
constexpr int kB = 256;
constexpr int kL = 3;
constexpr float kEps = 1e-5f;

constexpr int kShift = 7;                          // 128 nodes per bucket
constexpr int kNBuk = (kN + 127) >> 7;             // 391
constexpr int kEPB = 8192;                         // edges per binning block
constexpr int kNBinBlk = (kE + kEPB - 1) / kEPB;   // 98

// merged-prep per-thread range offsets (after the kNBinBlk hist blocks)
constexpr int kPxc = kN * kD / 8;                  // 800000 xconv items
constexpr int kPbnd = kPxc + kN + 1;               // bounds items
constexpr int kPw1 = kPbnd + kL * kD * kD;         // W1 conv
constexpr int kPw2 = kPw1 + kL * kD * kD;          // W2 conv
constexpr int kPzero = kPw2 + 768;                 // BN-stats zero (float4 each)
constexpr int kPrepThreadBlks = (kPzero + 255) / 256;

typedef __attribute__((ext_vector_type(8))) short short8;
typedef __attribute__((ext_vector_type(4))) float f32x4;

__device__ __forceinline__ float4 bnrelu4(float4 v, float4 sc, float4 sh) {
  float4 r;
  r.x = fmaxf(fmaf(v.x, sc.x, sh.x), 0.f);
  r.y = fmaxf(fmaf(v.y, sc.y, sh.y), 0.f);
  r.z = fmaxf(fmaf(v.z, sc.z, sh.z), 0.f);
  r.w = fmaxf(fmaf(v.w, sc.w, sh.w), 0.f);
  return r;
}

__device__ __forceinline__ void acc4(float4& a, const float4& v) {
  a.x += v.x; a.y += v.y; a.z += v.z; a.w += v.w;
}
__device__ __forceinline__ void accsq4(float4& a, const float4& v) {
  a.x = fmaf(v.x, v.x, a.x); a.y = fmaf(v.y, v.y, a.y);
  a.z = fmaf(v.z, v.z, a.z); a.w = fmaf(v.w, v.w, a.w);
}

// fp32 -> bf16 round-to-nearest-even
__device__ __forceinline__ unsigned int f2bf(float x) {
  unsigned int u = __float_as_uint(x);
  u = u + 0x7FFFu + ((u >> 16) & 1u);
  return u >> 16;
}
__device__ __forceinline__ float bf2f(unsigned int lo16) {
  return __uint_as_float(lo16 << 16);
}
__device__ __forceinline__ float bfhi(unsigned int u) {
  return __uint_as_float(u & 0xFFFF0000u);
}

// BN scale/shift from raw stats
__device__ __forceinline__ void bnmake(float su, float sq, float ga, float be,
                                       float& sc, float& sh) {
  float mu = su * (1.f / kN);
  float var = fmaf(-mu, mu, sq * (1.f / kN));
  float s = ga * rsqrtf(var + kEps);
  sc = s;
  sh = fmaf(-mu, s, be);
}

// ---------------- merged preprocessing ----------------
__global__ __launch_bounds__(256) void k_prep(
    const float* __restrict__ x, const int* __restrict__ ei,
    const int* __restrict__ bat, const float* __restrict__ W1,
    const float* __restrict__ W2, unsigned short* __restrict__ x16,
    int* __restrict__ bcnt, int* __restrict__ gstart,
    unsigned short* __restrict__ Wf1, unsigned short* __restrict__ Wf2,
    float* __restrict__ wsf) {
  __shared__ int cnt[kNBuk];
  if (blockIdx.x < (unsigned)kNBinBlk) {
    const int tid = threadIdx.x;
    const int e0 = blockIdx.x * kEPB;
    for (int t = tid; t < kNBuk; t += 256) cnt[t] = 0;
    __syncthreads();
#pragma unroll
    for (int i = 0; i < 32; ++i) {
      int e = e0 + i * 256 + tid;
      if (e < kE) atomicAdd(&cnt[ei[kE + e] >> kShift], 1);
    }
    __syncthreads();
    for (int t = tid; t < kNBuk; t += 256)
      bcnt[blockIdx.x * kNBuk + t] = cnt[t];
    return;
  }
  int idx = (blockIdx.x - kNBinBlk) * 256 + threadIdx.x;
  if (idx < kPxc) {
    const float* ap = x + (size_t)idx * 8;
    float4 v0 = *reinterpret_cast<const float4*>(ap);
    float4 v1 = *reinterpret_cast<const float4*>(ap + 4);
    short8 u;
    u[0] = (short)f2bf(v0.x); u[1] = (short)f2bf(v0.y);
    u[2] = (short)f2bf(v0.z); u[3] = (short)f2bf(v0.w);
    u[4] = (short)f2bf(v1.x); u[5] = (short)f2bf(v1.y);
    u[6] = (short)f2bf(v1.z); u[7] = (short)f2bf(v1.w);
    *reinterpret_cast<short8*>(x16 + (size_t)idx * 8) = u;
  } else if (idx < kPbnd) {
    int n = idx - kPxc;
    int b = (n < kN) ? bat[n] : kB;
    int bp = (n > 0) ? bat[n - 1] : -1;
    for (int g = bp + 1; g <= b; ++g) gstart[g] = n;
  } else if (idx < kPw2) {
    const float* W = (idx < kPw1) ? W1 : W2;
    unsigned short* Wf = (idx < kPw1) ? Wf1 : Wf2;
    int id2 = idx - ((idx < kPw1) ? kPbnd : kPw1);
    int m = id2 & (kD * kD - 1);
    int w = id2 >> 14;
    int k = m >> 7, col = m & 127;
    int kb = k >> 5, cb = col >> 4;
    int lane = (col & 15) + 16 * ((k & 31) >> 3);
    int j = k & 7;
    Wf[(size_t)w * kD * kD + ((size_t)(kb * 8 + cb) * 64 + lane) * 8 + j] =
        (unsigned short)f2bf(W[id2]);
  } else if (idx < kPzero) {
    int z = idx - kPw2;
    reinterpret_cast<float4*>(wsf)[z] = make_float4(0.f, 0.f, 0.f, 0.f);
  }
}

// single block: column-sum bcnt + exclusive scan -> bstart[0..391], bcur
__global__ __launch_bounds__(512) void k_scanB(const int* __restrict__ bcnt,
                                               int* __restrict__ bstart,
                                               int* __restrict__ bcur) {
  __shared__ int wsum[8];
  const int tid = threadIdx.x;
  const int lane = tid & 63, wid = tid >> 6;
  int v = 0;
  if (tid < kNBuk) {
    for (int blk = 0; blk < kNBinBlk; ++blk) v += bcnt[blk * kNBuk + tid];
  }
  int inc = v;
#pragma unroll
  for (int off = 1; off < 64; off <<= 1) {
    int t = __shfl_up(inc, off);
    if (lane >= off) inc += t;
  }
  if (lane == 63) wsum[wid] = inc;
  __syncthreads();
  int wpre = 0;
#pragma unroll
  for (int k = 0; k < 8; ++k) {
    int t = wsum[k];
    if (k < wid) wpre += t;
  }
  int excl = wpre + inc - v;
  if (tid <= kNBuk) {
    bstart[tid] = excl;
    if (tid < kNBuk) bcur[tid] = excl;
  }
}

// bin edges into dst-buckets as packed (dst<<16)|src, block-aggregated
__global__ __launch_bounds__(256) void k_binpairs(
    const int* __restrict__ ei, int* __restrict__ bcur,
    unsigned int* __restrict__ pairs) {
  __shared__ int cnt[kNBuk];
  __shared__ int base[kNBuk];
  const int tid = threadIdx.x;
  const int e0 = blockIdx.x * kEPB;
  for (int t = tid; t < kNBuk; t += 256) cnt[t] = 0;
  __syncthreads();
  unsigned int dr[32];
#pragma unroll
  for (int i = 0; i < 32; ++i) {
    int e = e0 + i * 256 + tid;
    unsigned int v = 0xFFFFFFFFu;
    if (e < kE) {
      int d = ei[kE + e];
      int r = atomicAdd(&cnt[d >> kShift], 1);
      v = ((unsigned int)d << 16) | (unsigned int)r;
    }
    dr[i] = v;
  }
  __syncthreads();
  for (int t = tid; t < kNBuk; t += 256) {
    int c = cnt[t];
    base[t] = (c > 0) ? atomicAdd(&bcur[t], c) : 0;
  }
  __syncthreads();
#pragma unroll
  for (int i = 0; i < 32; ++i) {
    unsigned int v = dr[i];
    if (v == 0xFFFFFFFFu) continue;
    int e = e0 + i * 256 + tid;
    unsigned int s = (unsigned int)ei[e];
    int b = (int)(v >> 16) >> kShift;
    int pos = base[b] + (int)(v & 0xFFFFu);
    pairs[pos] = (v & 0xFFFF0000u) | s;
  }
}

// one block per bucket: build rowptr for its 128 nodes, then scatter srcs
__global__ __launch_bounds__(256) void k_csrfill(
    const unsigned int* __restrict__ pairs, const int* __restrict__ bstart,
    int* __restrict__ rowptr, int* __restrict__ srcs) {
  __shared__ int cnt[128];
  __shared__ int cur[128];
  __shared__ int w0tot;
  const int b = blockIdx.x;
  const int tid = threadIdx.x;
  const int n0 = b << kShift;
  const int pb = bstart[b];
  const int pe = bstart[b + 1];
  if (tid < 128) cnt[tid] = 0;
  __syncthreads();
  for (int p = pb + tid; p < pe; p += 256)
    atomicAdd(&cnt[(int)(pairs[p] >> 16) - n0], 1);
  __syncthreads();
  int v = 0, inc = 0;
  if (tid < 128) {
    v = cnt[tid];
    inc = v;
#pragma unroll
    for (int off = 1; off < 64; off <<= 1) {
      int t = __shfl_up(inc, off);
      if ((tid & 63) >= off) inc += t;
    }
    if (tid == 63) w0tot = inc;
  }
  __syncthreads();
  if (tid < 128) {
    int excl = inc - v + ((tid >= 64) ? w0tot : 0);
    int n = n0 + tid;
    if (n <= kN) rowptr[n] = pb + excl;
    cur[tid] = pb + excl;
  }
  __syncthreads();
  for (int p = pb + tid; p < pe; p += 256) {
    unsigned int u = pairs[p];
    int local = (int)(u >> 16) - n0;
    int pos = atomicAdd(&cur[local], 1);
    srcs[pos] = (int)(u & 0xFFFFu);
  }
}

// ---------------- aggregation (12500 blocks; unroll-8, clamped tail) ----
template <bool BN>
__global__ __launch_bounds__(256) void k_gather(
    const unsigned int* __restrict__ h16, const int* __restrict__ rowptr,
    const int* __restrict__ srcs, const float* __restrict__ stats,
    const float* __restrict__ gam, const float* __restrict__ bet,
    unsigned int* __restrict__ agg16) {
  const int node = blockIdx.x * 4 + (threadIdx.x >> 6);
  const int lane = threadIdx.x & 63;
  float scx, scy, shx, shy;
  if (BN) {
    int c = lane * 2;
    bnmake(stats[c], stats[kD + c], gam[c], bet[c], scx, shx);
    bnmake(stats[c + 1], stats[kD + c + 1], gam[c + 1], bet[c + 1], scy, shy);
  }
  unsigned int u = h16[(size_t)node * 64 + lane];
  float ax = bf2f(u & 0xFFFFu), ay = bfhi(u);
  if (BN) {
    ax = fmaxf(fmaf(ax, scx, shx), 0.f);
    ay = fmaxf(fmaf(ay, scy, shy), 0.f);
  }
  const int beg = __builtin_amdgcn_readfirstlane(rowptr[node]);
  const int end = __builtin_amdgcn_readfirstlane(rowptr[node + 1]);
  const int last = end - 1;
  for (int j0 = beg; j0 < end; j0 += 8) {
    unsigned int v[8];
#pragma unroll
    for (int q = 0; q < 8; ++q) {
      int s = srcs[min(j0 + q, last)];
      v[q] = h16[(size_t)s * 64 + lane];
    }
#pragma unroll
    for (int q = 0; q < 8; ++q) {
      float vx = bf2f(v[q] & 0xFFFFu), vy = bfhi(v[q]);
      if (BN) {
        vx = fmaxf(fmaf(vx, scx, shx), 0.f);
        vy = fmaxf(fmaf(vy, scy, shy), 0.f);
      }
      bool ok = (j0 + q) < end;
      ax += ok ? vx : 0.f;
      ay += ok ? vy : 0.f;
    }
  }
  agg16[(size_t)node * 64 + lane] = f2bf(ax) | (f2bf(ay) << 16);
}

// ---------------- MFMA GEMM + BN-stats (64-row tile, 782 blocks) ----------
// Y = f(A) @ W + bias; A,Y bf16; f = bnrelu from raw statsA (if BN).
// 256 thr = 4 waves; wave w owns cols w*32; 4 row-frags x 4 k-frags.
// LDS 16.9KB -> ~8 blocks/CU capacity; 2x grid of the 128-row version.
template <bool BN>
__global__ __launch_bounds__(256) void k_gemm(
    const unsigned short* __restrict__ A16, const unsigned short* __restrict__ Wf,
    const float* __restrict__ bias, const float* __restrict__ statsA,
    const float* __restrict__ gamA, const float* __restrict__ betA,
    unsigned short* __restrict__ Y16,
    float* __restrict__ s_sum, float* __restrict__ s_ss) {
  union SMem {
    unsigned short af[16 * 64 * 8];   // 16 frags x 64 lanes x 8 bf16 = 16KB
    float epi[32 * 132];              // one 32-row pass = 16.9KB
  };
  __shared__ SMem sm;

  const int tid = threadIdx.x;
  const int w = tid >> 6;
  const int lane = tid & 63;
  const int row0 = blockIdx.x * 64;

  short8 bfr[4][2];
#pragma unroll
  for (int kb = 0; kb < 4; ++kb)
#pragma unroll
    for (int c = 0; c < 2; ++c)
      bfr[kb][c] = *reinterpret_cast<const short8*>(
          Wf + ((size_t)(kb * 8 + (2 * w + c)) * 64 + lane) * 8);

  {
    const int rlow = tid >> 4;
    const int k0 = (tid & 15) * 8;
    const int kb = k0 >> 5;
    const int lif = rlow + 16 * ((k0 & 31) >> 3);
    float4 sc0, sc1, sh0, sh1;
    if (BN) {
      float4 su0 = *reinterpret_cast<const float4*>(statsA + k0);
      float4 su1 = *reinterpret_cast<const float4*>(statsA + k0 + 4);
      float4 sq0 = *reinterpret_cast<const float4*>(statsA + kD + k0);
      float4 sq1 = *reinterpret_cast<const float4*>(statsA + kD + k0 + 4);
      float4 ga0 = *reinterpret_cast<const float4*>(gamA + k0);
      float4 ga1 = *reinterpret_cast<const float4*>(gamA + k0 + 4);
      float4 be0 = *reinterpret_cast<const float4*>(betA + k0);
      float4 be1 = *reinterpret_cast<const float4*>(betA + k0 + 4);
      bnmake(su0.x, sq0.x, ga0.x, be0.x, sc0.x, sh0.x);
      bnmake(su0.y, sq0.y, ga0.y, be0.y, sc0.y, sh0.y);
      bnmake(su0.z, sq0.z, ga0.z, be0.z, sc0.z, sh0.z);
      bnmake(su0.w, sq0.w, ga0.w, be0.w, sc0.w, sh0.w);
      bnmake(su1.x, sq1.x, ga1.x, be1.x, sc1.x, sh1.x);
      bnmake(su1.y, sq1.y, ga1.y, be1.y, sc1.y, sh1.y);
      bnmake(su1.z, sq1.z, ga1.z, be1.z, sc1.z, sh1.z);
      bnmake(su1.w, sq1.w, ga1.w, be1.w, sc1.w, sh1.w);
    }
#pragma unroll
    for (int i = 0; i < 4; ++i) {
      int grow = row0 + rlow + 16 * i;
      short8 u = (short8)0;
      if (grow < kN) {
        u = *reinterpret_cast<const short8*>(A16 + (size_t)grow * kD + k0);
        if (BN) {
          float4 v0, v1;
          v0.x = bf2f((unsigned short)u[0]); v0.y = bf2f((unsigned short)u[1]);
          v0.z = bf2f((unsigned short)u[2]); v0.w = bf2f((unsigned short)u[3]);
          v1.x = bf2f((unsigned short)u[4]); v1.y = bf2f((unsigned short)u[5]);
          v1.z = bf2f((unsigned short)u[6]); v1.w = bf2f((unsigned short)u[7]);
          v0 = bnrelu4(v0, sc0, sh0);
          v1 = bnrelu4(v1, sc1, sh1);
          u[0] = (short)f2bf(v0.x); u[1] = (short)f2bf(v0.y);
          u[2] = (short)f2bf(v0.z); u[3] = (short)f2bf(v0.w);
          u[4] = (short)f2bf(v1.x); u[5] = (short)f2bf(v1.y);
          u[6] = (short)f2bf(v1.z); u[7] = (short)f2bf(v1.w);
        }
      }
      int frag = i * 4 + kb;
      *reinterpret_cast<short8*>(&sm.af[((size_t)frag * 64 + lif) * 8]) = u;
    }
  }
  __syncthreads();

  f32x4 acc[4][2];
#pragma unroll
  for (int rb = 0; rb < 4; ++rb) {
    acc[rb][0] = (f32x4){0.f, 0.f, 0.f, 0.f};
    acc[rb][1] = (f32x4){0.f, 0.f, 0.f, 0.f};
  }
#pragma unroll
  for (int kb = 0; kb < 4; ++kb) {
    short8 afr[4];
#pragma unroll
    for (int rb = 0; rb < 4; ++rb)
      afr[rb] = *reinterpret_cast<const short8*>(
          &sm.af[((size_t)(rb * 4 + kb) * 64 + lane) * 8]);
#pragma unroll
    for (int rb = 0; rb < 4; ++rb) {
      acc[rb][0] = __builtin_amdgcn_mfma_f32_16x16x32_bf16(afr[rb], bfr[kb][0],
                                                           acc[rb][0], 0, 0, 0);
      acc[rb][1] = __builtin_amdgcn_mfma_f32_16x16x32_bf16(afr[rb], bfr[kb][1],
                                                           acc[rb][1], 0, 0, 0);
    }
  }

  // epilogue: two 32-row passes through LDS
  const int col4 = tid & 31;
  const int rowg = tid >> 5;   // 0..7, owns 4 rows per pass
  float4 b4 = reinterpret_cast<const float4*>(bias)[col4];
  float4 ss = make_float4(0.f, 0.f, 0.f, 0.f);
  float4 qq = make_float4(0.f, 0.f, 0.f, 0.f);

#pragma unroll
  for (int p = 0; p < 2; ++p) {
    __syncthreads();
#pragma unroll
    for (int rb2 = 0; rb2 < 2; ++rb2) {
      int rb = p * 2 + rb2;
#pragma unroll
      for (int c = 0; c < 2; ++c) {
#pragma unroll
        for (int j = 0; j < 4; ++j) {
          sm.epi[(size_t)(rb2 * 16 + (lane >> 4) * 4 + j) * 132 +
                 w * 32 + c * 16 + (lane & 15)] = acc[rb][c][j];
        }
      }
    }
    __syncthreads();
#pragma unroll
    for (int i = 0; i < 4; ++i) {
      int lrow = rowg * 4 + i;
      int grow = row0 + p * 32 + lrow;
      float4 v = *reinterpret_cast<float4*>(&sm.epi[(size_t)lrow * 132 + col4 * 4]);
      acc4(v, b4);
      if (grow < kN) {
        uint2 pk;
        pk.x = f2bf(v.x) | (f2bf(v.y) << 16);
        pk.y = f2bf(v.z) | (f2bf(v.w) << 16);
        *reinterpret_cast<uint2*>(Y16 + (size_t)grow * kD + col4 * 4) = pk;
        acc4(ss, v);
        accsq4(qq, v);
      }
    }
  }

  // stats reduce
  __syncthreads();
  *reinterpret_cast<float4*>(&sm.epi[(size_t)rowg * 128 + col4 * 4]) = ss;
  *reinterpret_cast<float4*>(&sm.epi[1024 + (size_t)rowg * 128 + col4 * 4]) = qq;
  __syncthreads();
  if (tid < kD) {
    float s = 0.f;
#pragma unroll
    for (int j = 0; j < 8; ++j) s += sm.epi[j * 128 + tid];
    atomicAdd(&s_sum[tid], s);
  } else {
    int c = tid - kD;
    float s = 0.f;
#pragma unroll
    for (int j = 0; j < 8; ++j) s += sm.epi[1024 + j * 128 + c];
    atomicAdd(&s_ss[c], s);
  }
}

// segmented pool over sorted batch; bf16 h, inline BN, fp32 out
__global__ __launch_bounds__(256) void k_pool(
    const unsigned short* __restrict__ h16, const int* __restrict__ gstart,
    const float* __restrict__ stats, const float* __restrict__ gam,
    const float* __restrict__ bet, float* __restrict__ out) {
  const int g = blockIdx.x;
  const int q = threadIdx.x & 31;
  const int r = threadIdx.x >> 5;
  const int s = gstart[g], e = gstart[g + 1];
  float4 sc, sh;
  {
    int c = q * 4;
    bnmake(stats[c + 0], stats[kD + c + 0], gam[c + 0], bet[c + 0], sc.x, sh.x);
    bnmake(stats[c + 1], stats[kD + c + 1], gam[c + 1], bet[c + 1], sc.y, sh.y);
    bnmake(stats[c + 2], stats[kD + c + 2], gam[c + 2], bet[c + 2], sc.z, sh.z);
    bnmake(stats[c + 3], stats[kD + c + 3], gam[c + 3], bet[c + 3], sc.w, sh.w);
  }
  float4 acc = make_float4(0.f, 0.f, 0.f, 0.f);
  for (int n = s + r; n < e; n += 8) {
    uint2 u = *reinterpret_cast<const uint2*>(h16 + (size_t)n * kD + q * 4);
    float4 v;
    v.x = bf2f(u.x & 0xFFFFu);
    v.y = bfhi(u.x);
    v.z = bf2f(u.y & 0xFFFFu);
    v.w = bfhi(u.y);
    acc4(acc, bnrelu4(v, sc, sh));
  }
  __shared__ float4 red[8][32];
  red[r][q] = acc;
  __syncthreads();
  if (r == 0) {
    float4 t = acc;
#pragma unroll
    for (int j = 1; j < 8; ++j) acc4(t, red[j][q]);
    reinterpret_cast<float4*>(out)[(size_t)g * 32 + q] = t;
  }
}

extern "C" void kernel_launch(void* const* d_in, const int* in_sizes, int n_in,
                              void* d_out, int out_size, void* d_ws, size_t ws_size,
                              hipStream_t stream) {
  const float* x   = (const float*)d_in[0];
  const int*   ei  = (const int*)d_in[1];
  const int*   bat = (const int*)d_in[2];
  const float* W1  = (const float*)d_in[3];
  const float* b1  = (const float*)d_in[4];
  const float* g1  = (const float*)d_in[5];
  const float* be1 = (const float*)d_in[6];
  const float* W2  = (const float*)d_in[7];
  const float* b2  = (const float*)d_in[8];
  const float* g2  = (const float*)d_in[9];
  const float* be2 = (const float*)d_in[10];
  float* out = (float*)d_out;

  char* p = (char*)d_ws;
  float* wsf = (float*)p;                       p += 16384;
  unsigned short* x16 = (unsigned short*)p;     p += (size_t)kN * kD * 2;
  unsigned short* bufA = (unsigned short*)p;    p += (size_t)kN * kD * 2;
  unsigned short* bufB = (unsigned short*)p;    p += (size_t)kN * kD * 2;
  unsigned short* Wf1 = (unsigned short*)p;     p += (size_t)kL * kD * kD * 2;
  unsigned short* Wf2 = (unsigned short*)p;     p += (size_t)kL * kD * kD * 2;
  int* rowptr = (int*)p;                        p += (kN + 2) * 4;
  int* bstart = (int*)p;                        p += (kNBuk + 1) * 4;
  int* bcur = (int*)p;                          p += (kNBuk + 1) * 4;
  int* gstart = (int*)p;                        p += (kB + 2) * 4;
  int* bcnt = (int*)p;                          p += (size_t)kNBinBlk * kNBuk * 4;
  unsigned int* pairs = (unsigned int*)p;       p += (size_t)kE * 4;
  int* srcs = (int*)p;                          p += (size_t)kE * 4;

  // preprocessing (no memsets: bcnt fully written, wsf zeroed in prep)
  k_prep<<<kNBinBlk + kPrepThreadBlks, 256, 0, stream>>>(
      x, ei, bat, W1, W2, x16, bcnt, gstart, Wf1, Wf2, wsf);
  k_scanB<<<1, 512, 0, stream>>>(bcnt, bstart, bcur);
  k_binpairs<<<kNBinBlk, 256, 0, stream>>>(ei, bcur, pairs);
  k_csrfill<<<kNBuk, 256, 0, stream>>>(pairs, bstart, rowptr, srcs);

  // static buffers each layer: gather x16 -> bufA; gemm1 bufA -> bufB;
  // gemm2 bufB -> x16 (x16 dead after gather). pool reads x16.
  const float* curStats = nullptr;
  const float* curGam = nullptr;
  const float* curBet = nullptr;
  const int ngemm = (kN + 63) / 64;

  for (int l = 0; l < kL; ++l) {
    float* st1 = wsf + (size_t)(l * 2 + 0) * 512;
    float* st2 = wsf + (size_t)(l * 2 + 1) * 512;

    if (curStats == nullptr)
      k_gather<false><<<kN / 4, 256, 0, stream>>>(
          (const unsigned int*)x16, rowptr, srcs, nullptr, nullptr, nullptr,
          (unsigned int*)bufA);
    else
      k_gather<true><<<kN / 4, 256, 0, stream>>>(
          (const unsigned int*)x16, rowptr, srcs, curStats, curGam, curBet,
          (unsigned int*)bufA);

    k_gemm<false><<<ngemm, 256, 0, stream>>>(bufA, Wf1 + (size_t)l * kD * kD,
                                             b1 + l * kD, nullptr, nullptr,
                                             nullptr, bufB, st1, st1 + kD);

    k_gemm<true><<<ngemm, 256, 0, stream>>>(bufB, Wf2 + (size_t)l * kD * kD,
                                            b2 + l * kD, st1, g1 + l * kD,
                                            be1 + l * kD, x16, st2, st2 + kD);

    curStats = st2;
    curGam = g2 + l * kD;
    curBet = be2 + l * kD;
  }

  k_pool<<<kB, 256, 0, stream>>>(x16, gstart, curStats, curGam, curBet, out);
}

// Round 17
// 276.029 us; speedup vs baseline: 1.1861x; 1.1861x over previous
//
#include <hip/hip_runtime.h>

constexpr int kN = 50000;
constexpr int kE = 800000;
constexpr int kD = 128;
constexpr int kB = 256;
constexpr int kL = 3;
constexpr float kEps = 1e-5f;

constexpr int kShift = 7;                          // 128 nodes per bucket
constexpr int kNBuk = (kN + 127) >> 7;             // 391
constexpr int kEPB = 8192;                         // edges per binning block
constexpr int kNBinBlk = (kE + kEPB - 1) / kEPB;   // 98

// merged-prep per-thread range offsets (after the kNBinBlk hist blocks)
constexpr int kPxc = kN * kD / 8;                  // 800000 xconv items
constexpr int kPbnd = kPxc + kN + 1;               // bounds items
constexpr int kPw1 = kPbnd + kL * kD * kD;         // W1 conv
constexpr int kPw2 = kPw1 + kL * kD * kD;          // W2 conv
constexpr int kPzero = kPw2 + 768;                 // BN-stats zero (float4 each)
constexpr int kPrepThreadBlks = (kPzero + 255) / 256;

typedef __attribute__((ext_vector_type(8))) short short8;
typedef __attribute__((ext_vector_type(4))) float f32x4;

__device__ __forceinline__ float4 bnrelu4(float4 v, float4 sc, float4 sh) {
  float4 r;
  r.x = fmaxf(fmaf(v.x, sc.x, sh.x), 0.f);
  r.y = fmaxf(fmaf(v.y, sc.y, sh.y), 0.f);
  r.z = fmaxf(fmaf(v.z, sc.z, sh.z), 0.f);
  r.w = fmaxf(fmaf(v.w, sc.w, sh.w), 0.f);
  return r;
}

__device__ __forceinline__ void acc4(float4& a, const float4& v) {
  a.x += v.x; a.y += v.y; a.z += v.z; a.w += v.w;
}
__device__ __forceinline__ void accsq4(float4& a, const float4& v) {
  a.x = fmaf(v.x, v.x, a.x); a.y = fmaf(v.y, v.y, a.y);
  a.z = fmaf(v.z, v.z, a.z); a.w = fmaf(v.w, v.w, a.w);
}

// fp32 -> bf16 round-to-nearest-even
__device__ __forceinline__ unsigned int f2bf(float x) {
  unsigned int u = __float_as_uint(x);
  u = u + 0x7FFFu + ((u >> 16) & 1u);
  return u >> 16;
}
__device__ __forceinline__ float bf2f(unsigned int lo16) {
  return __uint_as_float(lo16 << 16);
}
__device__ __forceinline__ float bfhi(unsigned int u) {
  return __uint_as_float(u & 0xFFFF0000u);
}

// BN scale/shift from raw stats
__device__ __forceinline__ void bnmake(float su, float sq, float ga, float be,
                                       float& sc, float& sh) {
  float mu = su * (1.f / kN);
  float var = fmaf(-mu, mu, sq * (1.f / kN));
  float s = ga * rsqrtf(var + kEps);
  sc = s;
  sh = fmaf(-mu, s, be);
}

// ---------------- merged preprocessing ----------------
// blocks [0, kNBinBlk): per-block bucket histogram of dst -> bcnt[blk][buk]
// remaining blocks, per-thread ranges:
//   [0,kPxc) xconv | [kPxc,kPbnd) bounds | [kPbnd,kPw1) W1 | [kPw1,kPw2) W2 |
//   [kPw2,kPzero) zero BN-stats
__global__ __launch_bounds__(256) void k_prep(
    const float* __restrict__ x, const int* __restrict__ ei,
    const int* __restrict__ bat, const float* __restrict__ W1,
    const float* __restrict__ W2, unsigned short* __restrict__ x16,
    int* __restrict__ bcnt, int* __restrict__ gstart,
    unsigned short* __restrict__ Wf1, unsigned short* __restrict__ Wf2,
    float* __restrict__ wsf) {
  __shared__ int cnt[kNBuk];
  if (blockIdx.x < (unsigned)kNBinBlk) {
    const int tid = threadIdx.x;
    const int e0 = blockIdx.x * kEPB;
    for (int t = tid; t < kNBuk; t += 256) cnt[t] = 0;
    __syncthreads();
#pragma unroll
    for (int i = 0; i < 32; ++i) {
      int e = e0 + i * 256 + tid;
      if (e < kE) atomicAdd(&cnt[ei[kE + e] >> kShift], 1);
    }
    __syncthreads();
    for (int t = tid; t < kNBuk; t += 256)
      bcnt[blockIdx.x * kNBuk + t] = cnt[t];
    return;
  }
  int idx = (blockIdx.x - kNBinBlk) * 256 + threadIdx.x;
  if (idx < kPxc) {
    const float* ap = x + (size_t)idx * 8;
    float4 v0 = *reinterpret_cast<const float4*>(ap);
    float4 v1 = *reinterpret_cast<const float4*>(ap + 4);
    short8 u;
    u[0] = (short)f2bf(v0.x); u[1] = (short)f2bf(v0.y);
    u[2] = (short)f2bf(v0.z); u[3] = (short)f2bf(v0.w);
    u[4] = (short)f2bf(v1.x); u[5] = (short)f2bf(v1.y);
    u[6] = (short)f2bf(v1.z); u[7] = (short)f2bf(v1.w);
    *reinterpret_cast<short8*>(x16 + (size_t)idx * 8) = u;
  } else if (idx < kPbnd) {
    int n = idx - kPxc;
    int b = (n < kN) ? bat[n] : kB;
    int bp = (n > 0) ? bat[n - 1] : -1;
    for (int g = bp + 1; g <= b; ++g) gstart[g] = n;
  } else if (idx < kPw2) {
    const float* W = (idx < kPw1) ? W1 : W2;
    unsigned short* Wf = (idx < kPw1) ? Wf1 : Wf2;
    int id2 = idx - ((idx < kPw1) ? kPbnd : kPw1);
    int m = id2 & (kD * kD - 1);
    int w = id2 >> 14;
    int k = m >> 7, col = m & 127;
    int kb = k >> 5, cb = col >> 4;
    int lane = (col & 15) + 16 * ((k & 31) >> 3);
    int j = k & 7;
    Wf[(size_t)w * kD * kD + ((size_t)(kb * 8 + cb) * 64 + lane) * 8 + j] =
        (unsigned short)f2bf(W[id2]);
  } else if (idx < kPzero) {
    int z = idx - kPw2;
    reinterpret_cast<float4*>(wsf)[z] = make_float4(0.f, 0.f, 0.f, 0.f);
  }
}

// single block: column-sum bcnt + exclusive scan -> bstart[0..391], bcur
__global__ __launch_bounds__(512) void k_scanB(const int* __restrict__ bcnt,
                                               int* __restrict__ bstart,
                                               int* __restrict__ bcur) {
  __shared__ int wsum[8];
  const int tid = threadIdx.x;
  const int lane = tid & 63, wid = tid >> 6;
  int v = 0;
  if (tid < kNBuk) {
    for (int blk = 0; blk < kNBinBlk; ++blk) v += bcnt[blk * kNBuk + tid];
  }
  int inc = v;
#pragma unroll
  for (int off = 1; off < 64; off <<= 1) {
    int t = __shfl_up(inc, off);
    if (lane >= off) inc += t;
  }
  if (lane == 63) wsum[wid] = inc;
  __syncthreads();
  int wpre = 0;
#pragma unroll
  for (int k = 0; k < 8; ++k) {
    int t = wsum[k];
    if (k < wid) wpre += t;
  }
  int excl = wpre + inc - v;
  if (tid <= kNBuk) {
    bstart[tid] = excl;
    if (tid < kNBuk) bcur[tid] = excl;
  }
}

// bin edges into dst-buckets as packed (dst<<16)|src, block-aggregated
__global__ __launch_bounds__(256) void k_binpairs(
    const int* __restrict__ ei, int* __restrict__ bcur,
    unsigned int* __restrict__ pairs) {
  __shared__ int cnt[kNBuk];
  __shared__ int base[kNBuk];
  const int tid = threadIdx.x;
  const int e0 = blockIdx.x * kEPB;
  for (int t = tid; t < kNBuk; t += 256) cnt[t] = 0;
  __syncthreads();
  unsigned int dr[32];
#pragma unroll
  for (int i = 0; i < 32; ++i) {
    int e = e0 + i * 256 + tid;
    unsigned int v = 0xFFFFFFFFu;
    if (e < kE) {
      int d = ei[kE + e];
      int r = atomicAdd(&cnt[d >> kShift], 1);
      v = ((unsigned int)d << 16) | (unsigned int)r;
    }
    dr[i] = v;
  }
  __syncthreads();
  for (int t = tid; t < kNBuk; t += 256) {
    int c = cnt[t];
    base[t] = (c > 0) ? atomicAdd(&bcur[t], c) : 0;
  }
  __syncthreads();
#pragma unroll
  for (int i = 0; i < 32; ++i) {
    unsigned int v = dr[i];
    if (v == 0xFFFFFFFFu) continue;
    int e = e0 + i * 256 + tid;
    unsigned int s = (unsigned int)ei[e];
    int b = (int)(v >> 16) >> kShift;
    int pos = base[b] + (int)(v & 0xFFFFu);
    pairs[pos] = (v & 0xFFFF0000u) | s;
  }
}

// one block per bucket: build rowptr for its 128 nodes, then scatter srcs
__global__ __launch_bounds__(256) void k_csrfill(
    const unsigned int* __restrict__ pairs, const int* __restrict__ bstart,
    int* __restrict__ rowptr, int* __restrict__ srcs) {
  __shared__ int cnt[128];
  __shared__ int cur[128];
  __shared__ int w0tot;
  const int b = blockIdx.x;
  const int tid = threadIdx.x;
  const int n0 = b << kShift;
  const int pb = bstart[b];
  const int pe = bstart[b + 1];
  if (tid < 128) cnt[tid] = 0;
  __syncthreads();
  for (int p = pb + tid; p < pe; p += 256)
    atomicAdd(&cnt[(int)(pairs[p] >> 16) - n0], 1);
  __syncthreads();
  int v = 0, inc = 0;
  if (tid < 128) {
    v = cnt[tid];
    inc = v;
#pragma unroll
    for (int off = 1; off < 64; off <<= 1) {
      int t = __shfl_up(inc, off);
      if ((tid & 63) >= off) inc += t;
    }
    if (tid == 63) w0tot = inc;
  }
  __syncthreads();
  if (tid < 128) {
    int excl = inc - v + ((tid >= 64) ? w0tot : 0);
    int n = n0 + tid;
    if (n <= kN) rowptr[n] = pb + excl;
    cur[tid] = pb + excl;
  }
  __syncthreads();
  for (int p = pb + tid; p < pe; p += 256) {
    unsigned int u = pairs[p];
    int local = (int)(u >> 16) - n0;
    int pos = atomicAdd(&cur[local], 1);
    srcs[pos] = (int)(u & 0xFFFFu);
  }
}

// ---------------- aggregation (separate kernel: 12500 blocks for TLP) ----
// one wave per node; lane owns cols 2*lane..2*lane+1. unroll-8 with clamped
// tail: all 8 loads of the last group issue (MLP), contributions masked
// post-activation.
template <bool BN>
__global__ __launch_bounds__(256) void k_gather(
    const unsigned int* __restrict__ h16, const int* __restrict__ rowptr,
    const int* __restrict__ srcs, const float* __restrict__ stats,
    const float* __restrict__ gam, const float* __restrict__ bet,
    unsigned int* __restrict__ agg16) {
  const int node = blockIdx.x * 4 + (threadIdx.x >> 6);
  const int lane = threadIdx.x & 63;
  float scx, scy, shx, shy;
  if (BN) {
    int c = lane * 2;
    bnmake(stats[c], stats[kD + c], gam[c], bet[c], scx, shx);
    bnmake(stats[c + 1], stats[kD + c + 1], gam[c + 1], bet[c + 1], scy, shy);
  }
  unsigned int u = h16[(size_t)node * 64 + lane];
  float ax = bf2f(u & 0xFFFFu), ay = bfhi(u);
  if (BN) {
    ax = fmaxf(fmaf(ax, scx, shx), 0.f);
    ay = fmaxf(fmaf(ay, scy, shy), 0.f);
  }
  const int beg = __builtin_amdgcn_readfirstlane(rowptr[node]);
  const int end = __builtin_amdgcn_readfirstlane(rowptr[node + 1]);
  const int last = end - 1;
  for (int j0 = beg; j0 < end; j0 += 8) {
    unsigned int v[8];
#pragma unroll
    for (int q = 0; q < 8; ++q) {
      int s = srcs[min(j0 + q, last)];
      v[q] = h16[(size_t)s * 64 + lane];
    }
#pragma unroll
    for (int q = 0; q < 8; ++q) {
      float vx = bf2f(v[q] & 0xFFFFu), vy = bfhi(v[q]);
      if (BN) {
        vx = fmaxf(fmaf(vx, scx, shx), 0.f);
        vy = fmaxf(fmaf(vy, scy, shy), 0.f);
      }
      bool ok = (j0 + q) < end;
      ax += ok ? vx : 0.f;
      ay += ok ? vy : 0.f;
    }
  }
  agg16[(size_t)node * 64 + lane] = f2bf(ax) | (f2bf(ay) << 16);
}

// ---------------- MFMA GEMM + BN-stats ----------------
// Y = f(A) @ W + bias; A,Y bf16; f = bnrelu from raw statsA (if BN).
template <bool BN>
__global__ __launch_bounds__(256) void k_gemm(
    const unsigned short* __restrict__ A16, const unsigned short* __restrict__ Wf,
    const float* __restrict__ bias, const float* __restrict__ statsA,
    const float* __restrict__ gamA, const float* __restrict__ betA,
    unsigned short* __restrict__ Y16,
    float* __restrict__ s_sum, float* __restrict__ s_ss) {
  union SMem {
    unsigned short af[32 * 64 * 8];
    float epi[64 * 132];
  };
  __shared__ SMem sm;

  const int tid = threadIdx.x;
  const int w = tid >> 6;
  const int lane = tid & 63;
  const int row0 = blockIdx.x * 128;

  short8 bfr[4][2];
#pragma unroll
  for (int kb = 0; kb < 4; ++kb)
#pragma unroll
    for (int c = 0; c < 2; ++c)
      bfr[kb][c] = *reinterpret_cast<const short8*>(
          Wf + ((size_t)(kb * 8 + (2 * w + c)) * 64 + lane) * 8);

  {
    const int rlow = tid >> 4;
    const int k0 = (tid & 15) * 8;
    const int kb = k0 >> 5;
    const int lif = rlow + 16 * ((k0 & 31) >> 3);
    float4 sc0, sc1, sh0, sh1;
    if (BN) {
      float4 su0 = *reinterpret_cast<const float4*>(statsA + k0);
      float4 su1 = *reinterpret_cast<const float4*>(statsA + k0 + 4);
      float4 sq0 = *reinterpret_cast<const float4*>(statsA + kD + k0);
      float4 sq1 = *reinterpret_cast<const float4*>(statsA + kD + k0 + 4);
      float4 ga0 = *reinterpret_cast<const float4*>(gamA + k0);
      float4 ga1 = *reinterpret_cast<const float4*>(gamA + k0 + 4);
      float4 be0 = *reinterpret_cast<const float4*>(betA + k0);
      float4 be1 = *reinterpret_cast<const float4*>(betA + k0 + 4);
      bnmake(su0.x, sq0.x, ga0.x, be0.x, sc0.x, sh0.x);
      bnmake(su0.y, sq0.y, ga0.y, be0.y, sc0.y, sh0.y);
      bnmake(su0.z, sq0.z, ga0.z, be0.z, sc0.z, sh0.z);
      bnmake(su0.w, sq0.w, ga0.w, be0.w, sc0.w, sh0.w);
      bnmake(su1.x, sq1.x, ga1.x, be1.x, sc1.x, sh1.x);
      bnmake(su1.y, sq1.y, ga1.y, be1.y, sc1.y, sh1.y);
      bnmake(su1.z, sq1.z, ga1.z, be1.z, sc1.z, sh1.z);
      bnmake(su1.w, sq1.w, ga1.w, be1.w, sc1.w, sh1.w);
    }
#pragma unroll
    for (int i = 0; i < 8; ++i) {
      int grow = row0 + rlow + 16 * i;
      short8 u = (short8)0;
      if (grow < kN) {
        u = *reinterpret_cast<const short8*>(A16 + (size_t)grow * kD + k0);
        if (BN) {
          float4 v0, v1;
          v0.x = bf2f((unsigned short)u[0]); v0.y = bf2f((unsigned short)u[1]);
          v0.z = bf2f((unsigned short)u[2]); v0.w = bf2f((unsigned short)u[3]);
          v1.x = bf2f((unsigned short)u[4]); v1.y = bf2f((unsigned short)u[5]);
          v1.z = bf2f((unsigned short)u[6]); v1.w = bf2f((unsigned short)u[7]);
          v0 = bnrelu4(v0, sc0, sh0);
          v1 = bnrelu4(v1, sc1, sh1);
          u[0] = (short)f2bf(v0.x); u[1] = (short)f2bf(v0.y);
          u[2] = (short)f2bf(v0.z); u[3] = (short)f2bf(v0.w);
          u[4] = (short)f2bf(v1.x); u[5] = (short)f2bf(v1.y);
          u[6] = (short)f2bf(v1.z); u[7] = (short)f2bf(v1.w);
        }
      }
      int frag = i * 4 + kb;
      *reinterpret_cast<short8*>(&sm.af[((size_t)frag * 64 + lif) * 8]) = u;
    }
  }
  __syncthreads();

  f32x4 acc[8][2];
#pragma unroll
  for (int rb = 0; rb < 8; ++rb) {
    acc[rb][0] = (f32x4){0.f, 0.f, 0.f, 0.f};
    acc[rb][1] = (f32x4){0.f, 0.f, 0.f, 0.f};
  }
#pragma unroll
  for (int kb = 0; kb < 4; ++kb) {
    short8 afr[8];
#pragma unroll
    for (int rb = 0; rb < 8; ++rb)
      afr[rb] = *reinterpret_cast<const short8*>(
          &sm.af[((size_t)(rb * 4 + kb) * 64 + lane) * 8]);
#pragma unroll
    for (int rb = 0; rb < 8; ++rb) {
      acc[rb][0] = __builtin_amdgcn_mfma_f32_16x16x32_bf16(afr[rb], bfr[kb][0],
                                                           acc[rb][0], 0, 0, 0);
      acc[rb][1] = __builtin_amdgcn_mfma_f32_16x16x32_bf16(afr[rb], bfr[kb][1],
                                                           acc[rb][1], 0, 0, 0);
    }
  }

  const int col4 = tid & 31;
  const int rowg = tid >> 5;
  float4 b4 = reinterpret_cast<const float4*>(bias)[col4];
  float4 ss = make_float4(0.f, 0.f, 0.f, 0.f);
  float4 qq = make_float4(0.f, 0.f, 0.f, 0.f);

#pragma unroll
  for (int p = 0; p < 2; ++p) {
    __syncthreads();
#pragma unroll
    for (int rb4 = 0; rb4 < 4; ++rb4) {
      int rb = p * 4 + rb4;
#pragma unroll
      for (int c = 0; c < 2; ++c) {
#pragma unroll
        for (int j = 0; j < 4; ++j) {
          sm.epi[(size_t)(rb4 * 16 + (lane >> 4) * 4 + j) * 132 +
                 w * 32 + c * 16 + (lane & 15)] = acc[rb][c][j];
        }
      }
    }
    __syncthreads();
#pragma unroll
    for (int i = 0; i < 8; ++i) {
      int lrow = rowg * 8 + i;
      int grow = row0 + p * 64 + lrow;
      float4 v = *reinterpret_cast<float4*>(&sm.epi[(size_t)lrow * 132 + col4 * 4]);
      acc4(v, b4);
      if (grow < kN) {
        uint2 pk;
        pk.x = f2bf(v.x) | (f2bf(v.y) << 16);
        pk.y = f2bf(v.z) | (f2bf(v.w) << 16);
        *reinterpret_cast<uint2*>(Y16 + (size_t)grow * kD + col4 * 4) = pk;
        acc4(ss, v);
        accsq4(qq, v);
      }
    }
  }

  __syncthreads();
  *reinterpret_cast<float4*>(&sm.epi[(size_t)rowg * 128 + col4 * 4]) = ss;
  *reinterpret_cast<float4*>(&sm.epi[1024 + (size_t)rowg * 128 + col4 * 4]) = qq;
  __syncthreads();
  if (tid < kD) {
    float s = 0.f;
#pragma unroll
    for (int j = 0; j < 8; ++j) s += sm.epi[j * 128 + tid];
    atomicAdd(&s_sum[tid], s);
  } else {
    int c = tid - kD;
    float s = 0.f;
#pragma unroll
    for (int j = 0; j < 8; ++j) s += sm.epi[1024 + j * 128 + c];
    atomicAdd(&s_ss[c], s);
  }
}

// segmented pool over sorted batch; bf16 h, inline BN, fp32 out
__global__ __launch_bounds__(256) void k_pool(
    const unsigned short* __restrict__ h16, const int* __restrict__ gstart,
    const float* __restrict__ stats, const float* __restrict__ gam,
    const float* __restrict__ bet, float* __restrict__ out) {
  const int g = blockIdx.x;
  const int q = threadIdx.x & 31;
  const int r = threadIdx.x >> 5;
  const int s = gstart[g], e = gstart[g + 1];
  float4 sc, sh;
  {
    int c = q * 4;
    bnmake(stats[c + 0], stats[kD + c + 0], gam[c + 0], bet[c + 0], sc.x, sh.x);
    bnmake(stats[c + 1], stats[kD + c + 1], gam[c + 1], bet[c + 1], sc.y, sh.y);
    bnmake(stats[c + 2], stats[kD + c + 2], gam[c + 2], bet[c + 2], sc.z, sh.z);
    bnmake(stats[c + 3], stats[kD + c + 3], gam[c + 3], bet[c + 3], sc.w, sh.w);
  }
  float4 acc = make_float4(0.f, 0.f, 0.f, 0.f);
  for (int n = s + r; n < e; n += 8) {
    uint2 u = *reinterpret_cast<const uint2*>(h16 + (size_t)n * kD + q * 4);
    float4 v;
    v.x = bf2f(u.x & 0xFFFFu);
    v.y = bfhi(u.x);
    v.z = bf2f(u.y & 0xFFFFu);
    v.w = bfhi(u.y);
    acc4(acc, bnrelu4(v, sc, sh));
  }
  __shared__ float4 red[8][32];
  red[r][q] = acc;
  __syncthreads();
  if (r == 0) {
    float4 t = acc;
#pragma unroll
    for (int j = 1; j < 8; ++j) acc4(t, red[j][q]);
    reinterpret_cast<float4*>(out)[(size_t)g * 32 + q] = t;
  }
}

extern "C" void kernel_launch(void* const* d_in, const int* in_sizes, int n_in,
                              void* d_out, int out_size, void* d_ws, size_t ws_size,
                              hipStream_t stream) {
  const float* x   = (const float*)d_in[0];
  const int*   ei  = (const int*)d_in[1];
  const int*   bat = (const int*)d_in[2];
  const float* W1  = (const float*)d_in[3];
  const float* b1  = (const float*)d_in[4];
  const float* g1  = (const float*)d_in[5];
  const float* be1 = (const float*)d_in[6];
  const float* W2  = (const float*)d_in[7];
  const float* b2  = (const float*)d_in[8];
  const float* g2  = (const float*)d_in[9];
  const float* be2 = (const float*)d_in[10];
  float* out = (float*)d_out;

  char* p = (char*)d_ws;
  float* wsf = (float*)p;                       p += 16384;
  unsigned short* x16 = (unsigned short*)p;     p += (size_t)kN * kD * 2;
  unsigned short* bufA = (unsigned short*)p;    p += (size_t)kN * kD * 2;
  unsigned short* bufB = (unsigned short*)p;    p += (size_t)kN * kD * 2;
  unsigned short* Wf1 = (unsigned short*)p;     p += (size_t)kL * kD * kD * 2;
  unsigned short* Wf2 = (unsigned short*)p;     p += (size_t)kL * kD * kD * 2;
  int* rowptr = (int*)p;                        p += (kN + 2) * 4;
  int* bstart = (int*)p;                        p += (kNBuk + 1) * 4;
  int* bcur = (int*)p;                          p += (kNBuk + 1) * 4;
  int* gstart = (int*)p;                        p += (kB + 2) * 4;
  int* bcnt = (int*)p;                          p += (size_t)kNBinBlk * kNBuk * 4;
  unsigned int* pairs = (unsigned int*)p;       p += (size_t)kE * 4;
  int* srcs = (int*)p;                          p += (size_t)kE * 4;

  // preprocessing (no memsets: bcnt fully written, wsf zeroed in prep)
  k_prep<<<kNBinBlk + kPrepThreadBlks, 256, 0, stream>>>(
      x, ei, bat, W1, W2, x16, bcnt, gstart, Wf1, Wf2, wsf);
  k_scanB<<<1, 512, 0, stream>>>(bcnt, bstart, bcur);
  k_binpairs<<<kNBinBlk, 256, 0, stream>>>(ei, bcur, pairs);
  k_csrfill<<<kNBuk, 256, 0, stream>>>(pairs, bstart, rowptr, srcs);

  // static buffers each layer: gather x16 -> bufA; gemm1 bufA -> bufB;
  // gemm2 bufB -> x16 (x16 dead after gather). pool reads x16.
  const float* curStats = nullptr;
  const float* curGam = nullptr;
  const float* curBet = nullptr;
  const int ngemm = (kN + 127) / 128;

  for (int l = 0; l < kL; ++l) {
    float* st1 = wsf + (size_t)(l * 2 + 0) * 512;
    float* st2 = wsf + (size_t)(l * 2 + 1) * 512;

    if (curStats == nullptr)
      k_gather<false><<<kN / 4, 256, 0, stream>>>(
          (const unsigned int*)x16, rowptr, srcs, nullptr, nullptr, nullptr,
          (unsigned int*)bufA);
    else
      k_gather<true><<<kN / 4, 256, 0, stream>>>(
          (const unsigned int*)x16, rowptr, srcs, curStats, curGam, curBet,
          (unsigned int*)bufA);

    k_gemm<false><<<ngemm, 256, 0, stream>>>(bufA, Wf1 + (size_t)l * kD * kD,
                                             b1 + l * kD, nullptr, nullptr,
                                             nullptr, bufB, st1, st1 + kD);

    k_gemm<true><<<ngemm, 256, 0, stream>>>(bufB, Wf2 + (size_t)l * kD * kD,
                                            b2 + l * kD, st1, g1 + l * kD,
                                            be1 + l * kD, x16, st2, st2 + kD);

    curStats = st2;
    curGam = g2 + l * kD;
    curBet = be2 + l * kD;
  }

  k_pool<<<kB, 256, 0, stream>>>(x16, gstart, curStats, curGam, curBet, out);
}